// Round 11
// baseline (1056.429 us; speedup 1.0000x reference)
//
#include <hip/hip_runtime.h>
#include <math.h>

#define B_ 16
#define N_ 2048
#define D_ 1024
#define KTOP 100
#define RTOP 5
#define JCH 16

typedef __attribute__((ext_vector_type(8))) short short8;
typedef __attribute__((ext_vector_type(4))) float f32x4;

__device__ inline unsigned cvt_pk_bf16(float lo, float hi) {
  unsigned r;
  asm("v_cvt_pk_bf16_f32 %0, %1, %2" : "=v"(r) : "v"(lo), "v"(hi));
  return r;
}
__device__ inline float lo_bf(unsigned p) { return __uint_as_float(p << 16); }
__device__ inline float hi_bf(unsigned p) { return __uint_as_float(p & 0xFFFF0000u); }

// split 32 f32 (in 8 float4 regs) into h+m bf16 levels and write to LDS
__device__ inline void split_write(const float4* t8, short* dsth, short* dstm,
                                   int srow, int swz) {
#pragma unroll
  for (int j = 0; j < 4; ++j) {
    float4 ta = t8[2 * j];
    float4 tb = t8[2 * j + 1];
    unsigned h0 = cvt_pk_bf16(ta.x, ta.y);
    unsigned h1 = cvt_pk_bf16(ta.z, ta.w);
    unsigned h2 = cvt_pk_bf16(tb.x, tb.y);
    unsigned h3 = cvt_pk_bf16(tb.z, tb.w);
    float r0 = ta.x - lo_bf(h0), r1 = ta.y - hi_bf(h0);
    float r2 = ta.z - lo_bf(h1), r3 = ta.w - hi_bf(h1);
    float r4 = tb.x - lo_bf(h2), r5 = tb.y - hi_bf(h2);
    float r6 = tb.z - lo_bf(h3), r7 = tb.w - hi_bf(h3);
    unsigned m0 = cvt_pk_bf16(r0, r1);
    unsigned m1 = cvt_pk_bf16(r2, r3);
    unsigned m2 = cvt_pk_bf16(r4, r5);
    unsigned m3 = cvt_pk_bf16(r6, r7);
    const int off = srow * 32 + ((j ^ swz) << 3);
    *(int4*)(dsth + off) = make_int4(h0, h1, h2, h3);
    *(int4*)(dstm + off) = make_int4(m0, m1, m2, m3);
  }
}

// ---------------- Kernel A: MFMA row stats (m, l) over s = q k^T -----------
// 2-way bf16 split per operand (h+m), 4 MFMA products -> s error ~1e-4.
// 128x128 tile per block; 4 waves; double-buffered LDS (64 KB), 1 barrier/iter:
//   barrier -> issue loads(t+1) -> ds_read+MFMA buf[t&1] -> cvt+write buf[(t+1)&1]
__global__ __launch_bounds__(256) void rowstats_mfma(
    const float* __restrict__ q, const float* __restrict__ k,
    float* __restrict__ mpart, float* __restrict__ lpart) {
  __shared__ short Ah[2][128 * 32], Am[2][128 * 32];
  __shared__ short Bh[2][128 * 32], Bm[2][128 * 32];
  const int tid = threadIdx.x;
  const int wave = tid >> 6, lane = tid & 63;
  const int b = blockIdx.z;
  const int rb = blockIdx.x;   // row block (q)
  const int cb = blockIdx.y;   // col block (k) == j-chunk
  const float* qb = q + ((size_t)b * N_ + rb * 128) * D_;
  const float* kb = k + ((size_t)b * N_ + cb * 128) * D_;

  // staging role: threads 0-127 stage q rows, 128-255 stage k rows
  const int srow = tid & 127;
  const float* sbase = ((tid < 128) ? qb : kb) + (size_t)srow * D_;
  const int isB = (tid >> 7);  // 0 -> A side, 1 -> B side
  const int swz = (srow >> 1) & 3;

  f32x4 acc[2][8];
#pragma unroll
  for (int fr = 0; fr < 2; ++fr)
#pragma unroll
    for (int fc = 0; fc < 8; ++fc)
#pragma unroll
      for (int r = 0; r < 4; ++r) acc[fr][fc][r] = 0.0f;

  const int g = lane >> 4;      // K slot group (8 bf16 = 16B)
  const int rlo = lane & 15;    // token row within fragment

  // prologue: stage tile 0 into buffer 0
  {
    float4 pre[8];
#pragma unroll
    for (int i = 0; i < 8; ++i) pre[i] = ((const float4*)sbase)[i];
    split_write(pre, isB ? Bh[0] : Ah[0], isB ? Bm[0] : Am[0], srow, swz);
  }

  for (int kt = 0; kt < D_ / 32; ++kt) {
    __syncthreads();  // buf[kt&1] writes visible; buf[(kt+1)&1] reads (iter kt-1) done
    const int cur = kt & 1, nxt = cur ^ 1;
    // ---- issue prefetch loads for tile kt+1 (consumed after MFMA below) ----
    float4 pre[8];
    if (kt < D_ / 32 - 1) {
      const float* src = sbase + (kt + 1) * 32;
#pragma unroll
      for (int i = 0; i < 8; ++i) pre[i] = ((const float4*)src)[i];
    }
    // ---- compute: 2 row-frags x 8 col-frags x 4 products on buf[cur] ----
    const short* ahb = Ah[cur];
    const short* amb = Am[cur];
    const short* bhb = Bh[cur];
    const short* bmb = Bm[cur];
    short8 afh[2], afm[2];
#pragma unroll
    for (int fr = 0; fr < 2; ++fr) {
      const int R = (wave << 5) + (fr << 4) + rlo;
      const int off = R * 32 + ((g ^ ((R >> 1) & 3)) << 3);
      afh[fr] = *(const short8*)&ahb[off];
      afm[fr] = *(const short8*)&amb[off];
    }
#pragma unroll
    for (int fc = 0; fc < 8; ++fc) {
      const int Rb = (fc << 4) + rlo;
      const int offb = Rb * 32 + ((g ^ ((Rb >> 1) & 3)) << 3);
      short8 bh = *(const short8*)&bhb[offb];
      short8 bm = *(const short8*)&bmb[offb];
#pragma unroll
      for (int fr = 0; fr < 2; ++fr) {
        acc[fr][fc] = __builtin_amdgcn_mfma_f32_16x16x32_bf16(afh[fr], bh, acc[fr][fc], 0, 0, 0);
        acc[fr][fc] = __builtin_amdgcn_mfma_f32_16x16x32_bf16(afh[fr], bm, acc[fr][fc], 0, 0, 0);
        acc[fr][fc] = __builtin_amdgcn_mfma_f32_16x16x32_bf16(afm[fr], bh, acc[fr][fc], 0, 0, 0);
        acc[fr][fc] = __builtin_amdgcn_mfma_f32_16x16x32_bf16(afm[fr], bm, acc[fr][fc], 0, 0, 0);
      }
    }
    // ---- convert prefetched tile and write to the other buffer ----
    if (kt < D_ / 32 - 1) {
      split_write(pre, isB ? Bh[nxt] : Ah[nxt], isB ? Bm[nxt] : Am[nxt], srow, swz);
    }
  }

  // ---- epilogue: per-row max & exp-sum over this 128-col chunk ----
  // C/D layout: col = lane&15, row = (lane>>4)*4 + reg  (within 16x16 frag)
#pragma unroll
  for (int fr = 0; fr < 2; ++fr) {
#pragma unroll
    for (int r = 0; r < 4; ++r) {
      float vmax = acc[fr][0][r];
#pragma unroll
      for (int fc = 1; fc < 8; ++fc) vmax = fmaxf(vmax, acc[fr][fc][r]);
#pragma unroll
      for (int m = 1; m < 16; m <<= 1) vmax = fmaxf(vmax, __shfl_xor(vmax, m));
      float s = 0.0f;
#pragma unroll
      for (int fc = 0; fc < 8; ++fc) s += __expf(acc[fr][fc][r] - vmax);
#pragma unroll
      for (int m = 1; m < 16; m <<= 1) s += __shfl_xor(s, m);
      if ((lane & 15) == 0) {
        const int row = (wave << 5) + (fr << 4) + ((lane >> 4) << 2) + r;
        size_t o = ((size_t)b * JCH + cb) * N_ + rb * 128 + row;
        mpart[o] = vmax;
        lpart[o] = s;
      }
    }
  }
}

// ---------------- Kernel A2: combine partial (m,l) across j-chunks ---------
__global__ __launch_bounds__(256) void combine_kernel(
    const float* __restrict__ mpart, const float* __restrict__ lpart,
    float* __restrict__ mfin, float* __restrict__ lfin) {
  int r = blockIdx.x * 256 + threadIdx.x;
  int b = r >> 11;
  int i = r & (N_ - 1);
  float m = -INFINITY, l = 0.0f;
  for (int jc = 0; jc < JCH; ++jc) {
    size_t o = ((size_t)b * JCH + jc) * N_ + i;
    float mp = mpart[o], lp = lpart[o];
    float mn = fmaxf(m, mp);
    l = l * __expf(m - mn) + lp * __expf(mp - mn);
    m = mn;
  }
  mfin[r] = m;
  lfin[r] = l;
}

// ---------------- Kernel B: diagonal softmax values ------------------------
__global__ __launch_bounds__(256) void diag_kernel(
    const float* __restrict__ q, const float* __restrict__ k,
    const float* __restrict__ mfin, const float* __restrict__ lfin,
    float* __restrict__ diag) {
  int wave = threadIdx.x >> 6, lane = threadIdx.x & 63;
  int row = blockIdx.x * 4 + wave;  // 0 .. B_*N_-1
  int b = row >> 11, i = row & (N_ - 1);
  const float* qr = q + ((size_t)b * N_ + i) * D_;
  const float* kr = k + ((size_t)b * N_ + i) * D_;
  float s = 0.0f;
  for (int t = 0; t < D_ / 64; ++t) s = fmaf(qr[lane + (t << 6)], kr[lane + (t << 6)], s);
  for (int m = 1; m < 64; m <<= 1) s += __shfl_xor(s, m);
  if (lane == 0) diag[row] = __expf(s - mfin[row]) / lfin[row];
}

// ---------------- Kernel C: per-batch top-100 of diag, sorted ascending ----
__global__ __launch_bounds__(256) void top100_kernel(
    const float* __restrict__ diag, int* __restrict__ inst_idx) {
  __shared__ float sval[N_];
  __shared__ int sidx[N_];
  __shared__ int top[128];
  int b = blockIdx.x, tid = threadIdx.x;
  for (int i = tid; i < N_; i += 256) { sval[i] = diag[(size_t)b * N_ + i]; sidx[i] = i; }
  __syncthreads();
  // bitonic sort: value descending, tie -> lower index first (lax.top_k order)
  for (int ksz = 2; ksz <= N_; ksz <<= 1) {
    for (int j = ksz >> 1; j > 0; j >>= 1) {
      for (int t = tid; t < N_; t += 256) {
        int x = t ^ j;
        if (x > t) {
          float va = sval[t], vb = sval[x];
          int ia = sidx[t], ib = sidx[x];
          bool agtb = (va > vb) || (va == vb && ia < ib);
          bool up = ((t & ksz) == 0);
          if (up != agtb) { sval[t] = vb; sval[x] = va; sidx[t] = ib; sidx[x] = ia; }
        }
      }
      __syncthreads();
    }
  }
  if (tid < 128) top[tid] = (tid < KTOP) ? sidx[tid] : 0x7FFFFFFF;
  __syncthreads();
  // sort the 100 winners' indices ascending (bitonic over 128 with +inf pad)
  for (int ksz = 2; ksz <= 128; ksz <<= 1) {
    for (int j = ksz >> 1; j > 0; j >>= 1) {
      if (tid < 128) {
        int t = tid, x = t ^ j;
        if (x > t) {
          int ia = top[t], ib = top[x];
          bool up = ((t & ksz) == 0);
          bool altb = ia < ib;
          if (up != altb) { top[t] = ib; top[x] = ia; }
        }
      }
      __syncthreads();
    }
  }
  if (tid < KTOP) inst_idx[b * KTOP + tid] = top[tid];
}

// ---------------- Kernel D: rel 100x100, mask diag, top-5 per row ----------
__global__ __launch_bounds__(256) void reltop_kernel(
    const float* __restrict__ q, const float* __restrict__ k,
    const float* __restrict__ mfin, const float* __restrict__ lfin,
    const int* __restrict__ inst_idx, float* __restrict__ out0,
    int* __restrict__ pairs) {
  __shared__ int inst[KTOP];
  __shared__ float qv[D_];
  __shared__ float sv[KTOP];
  int a = blockIdx.x, b = blockIdx.y, tid = threadIdx.x;
  if (tid < KTOP) inst[tid] = inst_idx[b * KTOP + tid];
  __syncthreads();
  int ia = inst[a];
  const float* qrow = q + ((size_t)b * N_ + ia) * D_;
  for (int t = tid; t < D_; t += 256) qv[t] = qrow[t];
  __syncthreads();
  int wave = tid >> 6, lane = tid & 63;
  for (int c0 = 0; c0 < KTOP; c0 += 4) {
    int c = c0 + wave;
    const float* krow = k + ((size_t)b * N_ + inst[c]) * D_;
    float s = 0.0f;
    for (int t = 0; t < D_ / 64; ++t) s = fmaf(qv[lane + (t << 6)], krow[lane + (t << 6)], s);
    for (int m = 1; m < 64; m <<= 1) s += __shfl_xor(s, m);
    if (lane == 0) sv[c] = s;
  }
  __syncthreads();
  if (tid < 64) {
    float mi = mfin[(size_t)b * N_ + ia];
    float li = lfin[(size_t)b * N_ + ia];
    float c0v = (tid == a) ? 1e9f : __expf(sv[tid] - mi) / li;
    int c0i = tid;
    float c1v = -1.0f;
    int c1i = 1 << 20;
    if (tid + 64 < KTOP) {
      c1v = (tid + 64 == a) ? 1e9f : __expf(sv[tid + 64] - mi) / li;
      c1i = tid + 64;
    }
    int sel[RTOP];
    for (int rr = 0; rr < RTOP; ++rr) {
      float v;
      int idx;
      if (c1v > c0v || (c1v == c0v && c1i < c0i)) { v = c1v; idx = c1i; }
      else { v = c0v; idx = c0i; }
      for (int m = 1; m < 64; m <<= 1) {
        float ov = __shfl_xor(v, m);
        int oi = __shfl_xor(idx, m);
        if (ov > v || (ov == v && oi < idx)) { v = ov; idx = oi; }
      }
      sel[rr] = idx;
      if (idx == c0i) c0v = -2.0f;
      if (idx == c1i) c1v = -2.0f;
    }
    if (lane == 0) {
      for (int i2 = 0; i2 < RTOP; ++i2)
        for (int j2 = 0; j2 < RTOP - 1 - i2; ++j2)
          if (sel[j2] > sel[j2 + 1]) { int tswap = sel[j2]; sel[j2] = sel[j2 + 1]; sel[j2 + 1] = tswap; }
      for (int rr = 0; rr < RTOP; ++rr) {
        size_t ri = (size_t)b * KTOP * RTOP + (size_t)a * RTOP + rr;
        out0[ri * 3 + 0] = (float)b;
        out0[ri * 3 + 1] = (float)ia;
        out0[ri * 3 + 2] = (float)inst[sel[rr]];
        pairs[ri * 2 + 0] = ia;
        pairs[ri * 2 + 1] = inst[sel[rr]];
      }
    }
  }
}

// ---------------- Kernel E: gather + add + LayerNorm -----------------------
__global__ __launch_bounds__(256) void embed_kernel(
    const float* __restrict__ q, const int* __restrict__ pairs,
    float* __restrict__ out1) {
  __shared__ float red[8];
  int r = blockIdx.x, b = blockIdx.y, tid = threadIdx.x;
  size_t ri = (size_t)b * KTOP * RTOP + r;
  int subj = pairs[ri * 2 + 0], obj = pairs[ri * 2 + 1];
  const float* qs = q + ((size_t)b * N_ + subj) * D_;
  const float* qo = q + ((size_t)b * N_ + obj) * D_;
  float4 v1 = *(const float4*)(qs + tid * 4);
  float4 v2 = *(const float4*)(qo + tid * 4);
  float x0 = v1.x + v2.x, x1 = v1.y + v2.y, x2 = v1.z + v2.z, x3 = v1.w + v2.w;
  float s = x0 + x1 + x2 + x3;
  float qq = x0 * x0 + x1 * x1 + x2 * x2 + x3 * x3;
  int lane = tid & 63, wave = tid >> 6;
  for (int m = 1; m < 64; m <<= 1) { s += __shfl_xor(s, m); qq += __shfl_xor(qq, m); }
  if (lane == 0) { red[wave] = s; red[4 + wave] = qq; }
  __syncthreads();
  float S = red[0] + red[1] + red[2] + red[3];
  float Q = red[4] + red[5] + red[6] + red[7];
  float mu = S * (1.0f / D_);
  float var = Q * (1.0f / D_) - mu * mu;
  float rstd = 1.0f / sqrtf(var + 1e-5f);
  float4 o;
  o.x = (x0 - mu) * rstd;
  o.y = (x1 - mu) * rstd;
  o.z = (x2 - mu) * rstd;
  o.w = (x3 - mu) * rstd;
  *(float4*)(out1 + ri * D_ + tid * 4) = o;
}

extern "C" void kernel_launch(void* const* d_in, const int* in_sizes, int n_in,
                              void* d_out, int out_size, void* d_ws, size_t ws_size,
                              hipStream_t stream) {
  (void)in_sizes; (void)n_in; (void)out_size; (void)ws_size;
  const float* q = (const float*)d_in[0];
  const float* k = (const float*)d_in[1];
  float* out = (float*)d_out;

  char* ws = (char*)d_ws;
  float* mpart = (float*)ws; ws += (size_t)B_ * JCH * N_ * 4;
  float* lpart = (float*)ws; ws += (size_t)B_ * JCH * N_ * 4;
  float* mfin = (float*)ws;  ws += (size_t)B_ * N_ * 4;
  float* lfin = (float*)ws;  ws += (size_t)B_ * N_ * 4;
  float* diag = (float*)ws;  ws += (size_t)B_ * N_ * 4;
  int* inst = (int*)ws;      ws += (size_t)B_ * KTOP * 4;
  int* pairs = (int*)ws;     // B_*KTOP*RTOP*2 ints

  hipLaunchKernelGGL(rowstats_mfma, dim3(N_ / 128, N_ / 128, B_), dim3(256), 0, stream,
                     q, k, mpart, lpart);
  hipLaunchKernelGGL(combine_kernel, dim3(B_ * N_ / 256), dim3(256), 0, stream,
                     mpart, lpart, mfin, lfin);
  hipLaunchKernelGGL(diag_kernel, dim3(B_ * N_ / 4), dim3(256), 0, stream,
                     q, k, mfin, lfin, diag);
  hipLaunchKernelGGL(top100_kernel, dim3(B_), dim3(256), 0, stream, diag, inst);
  hipLaunchKernelGGL(reltop_kernel, dim3(KTOP, B_), dim3(256), 0, stream,
                     q, k, mfin, lfin, inst, out, pairs);
  hipLaunchKernelGGL(embed_kernel, dim3(KTOP * RTOP, B_), dim3(256), 0, stream,
                     q, pairs, out + (size_t)B_ * KTOP * RTOP * 3);
}